// Round 13
// baseline (166.982 us; speedup 1.0000x reference)
//
#include <hip/hip_runtime.h>
#include <hip/hip_bf16.h>
#include <math.h>

#define NNODES 100000
#define NEDGES 600000
#define DD 128
#define SCAN_B 512
#define NFRAGS 6250          // NNODES / 16
#define TGRID 512            // fusedT grid: 2 blocks/CU

// prep1 block ranges (mode 2). x-convert needs NNODES*DD/8/256 = 6250 blocks.
#define P1_W 48
#define P1_X (P1_W + 6250)            // 6298
#define P1_H (P1_X + (NEDGES + 255) / 256)   // 6298 + 2344 = 8642

typedef __attribute__((ext_vector_type(8))) short bf16x8;
typedef __attribute__((ext_vector_type(4))) float f32x4;
typedef __attribute__((ext_vector_type(4))) unsigned short u16x4;

static __device__ __forceinline__ unsigned short f2bf(float f) {
    __hip_bfloat16 h = __float2bfloat16(f);   // HW RNE cvt
    return __builtin_bit_cast(unsigned short, h);
}
static __device__ __forceinline__ float bf2f(unsigned short h) {
    unsigned u = ((unsigned)h) << 16;
    return __builtin_bit_cast(float, u);
}
// tanh-approx GELU via sigmoid, exp2-folded; fast rcp instead of IEEE divide.
// |err| <= ~3e-3 absolute vs exact-erf (threshold 1.07).
static __device__ __forceinline__ float gelu_fast(float v) {
    float w = v * (-2.302203846f - 0.102943150f * v * v);
#if __has_builtin(__builtin_amdgcn_exp2f)
    float e = __builtin_amdgcn_exp2f(w);
#else
    float e = exp2f(w);
#endif
#if __has_builtin(__builtin_amdgcn_rcpf)
    return v * __builtin_amdgcn_rcpf(1.0f + e);
#else
    return v / (1.0f + e);
#endif
}

#if __has_builtin(__builtin_amdgcn_global_load_lds)
#define HAVE_GLDS 1
#else
#define HAVE_GLDS 0
#endif

static __device__ __forceinline__ void gload_lds16(const unsigned short* g, unsigned short* s, int lane) {
#if HAVE_GLDS
    (void)lane;
    __builtin_amdgcn_global_load_lds((const __attribute__((address_space(1))) void*)g,
                                     (__attribute__((address_space(3))) void*)s, 16, 0, 0);
#else
    *(bf16x8*)(s + lane * 8) = *(const bf16x8*)g;
#endif
}
static __device__ __forceinline__ void gload_lds4(const float* g, unsigned short* s, int lane) {
#if HAVE_GLDS
    (void)lane;
    __builtin_amdgcn_global_load_lds((const __attribute__((address_space(1))) void*)g,
                                     (__attribute__((address_space(3))) void*)s, 4, 0, 0);
#else
    *(float*)((char*)s + lane * 4) = *g;
#endif
}

#define MFMA(a, b, c) __builtin_amdgcn_mfma_f32_16x16x32_bf16(a, b, c, 0, 0, 0)
#define BARX() do { asm volatile("s_waitcnt lgkmcnt(0)" ::: "memory"); \
                    __builtin_amdgcn_s_barrier(); } while (0)

// ---------- prep1 (mode 2): weights->fusedT frags | x->bf16 | hist ----------
// REQUIRES cnt zeroed beforehand (hipMemsetAsync on the stream).
// blocks: [0,P1_W) weights | [P1_W,P1_X) x-convert (6250 blks!) | [P1_X,P1_H) hist
__global__ __launch_bounds__(256) void prep1_k(const float* __restrict__ x,
                                               const float* __restrict__ Wn,
                                               const float* __restrict__ We,
                                               const float* __restrict__ Wu,
                                               const int* __restrict__ ei,
                                               unsigned short* __restrict__ wfrag,
                                               int* __restrict__ cnt,
                                               unsigned short* __restrict__ xb) {
    int b = blockIdx.x;
    int t = threadIdx.x;
    if (b < P1_W) {
        // frag g: Wn g<32 (nf=g>>2,kt=g&3) | We1 32..63 | We2 64..95 |
        //         Wu 96..191 (nf=gg/12, kt=gg%12)
        int tid = b * 256 + t;
        int l = tid & 63;
        int g = tid >> 6;
        int l16 = l & 15, lg8 = (l >> 4) * 8;
        const float* src;
        if (g < 32)       { int nf = g >> 2,        kt = g & 3;
                            src = Wn + (size_t)(nf * 16 + l16) * 128 + kt * 32 + lg8; }
        else if (g < 64)  { int gg = g - 32; int nf = gg >> 2, kt = gg & 3;
                            src = We + (size_t)(nf * 16 + l16) * 256 + kt * 32 + lg8; }
        else if (g < 96)  { int gg = g - 64; int nf = gg >> 2, kt = gg & 3;
                            src = We + (size_t)(nf * 16 + l16) * 256 + 128 + kt * 32 + lg8; }
        else              { int gg = g - 96; int nf = gg / 12, kt = gg % 12;
                            src = Wu + (size_t)(nf * 16 + l16) * 384 + kt * 32 + lg8; }
        unsigned short o[8];
#pragma unroll
        for (int j = 0; j < 8; ++j) o[j] = f2bf(src[j]);
        *(bf16x8*)(wfrag + (size_t)tid * 8) = *(bf16x8*)o;
    } else if (b < P1_X) {
        int i = (b - P1_W) * 256 + t;          // group of 8 floats
        if (i < NNODES * DD / 8) {
            float4 v0 = *(const float4*)(x + (size_t)i * 8);
            float4 v1 = *(const float4*)(x + (size_t)i * 8 + 4);
            unsigned short o[8] = { f2bf(v0.x), f2bf(v0.y), f2bf(v0.z), f2bf(v0.w),
                                    f2bf(v1.x), f2bf(v1.y), f2bf(v1.z), f2bf(v1.w) };
            *(bf16x8*)(xb + (size_t)i * 8) = *(bf16x8*)o;
        }
    } else {
        int e = (b - P1_X) * 256 + t;
        if (e < NEDGES) atomicAdd(&cnt[ei[e]], 1);
    }
}

// ---------- prep0 (fallback modes): fused4 frag layout | cnt zero | x->bf16 ----------
__global__ __launch_bounds__(256) void prep0_k(const float* __restrict__ x,
                                               const float* __restrict__ Wn,
                                               const float* __restrict__ We,
                                               const float* __restrict__ Wu,
                                               unsigned short* __restrict__ wfrag,
                                               int* __restrict__ cnt,
                                               unsigned short* __restrict__ xb) {
    int b = blockIdx.x;
    int t = threadIdx.x;
    if (b < 48) {
        int tid = b * 256 + t;
        int l = tid & 63;
        int ct = (tid >> 6) & 7;
        int kt = (tid >> 9) & 3;
        int tile = tid >> 11;
        int n = ct * 16 + (l & 15);
        int k = kt * 32 + (l >> 4) * 8;
        const float* src;
        switch (tile) {
            case 0:  src = Wn + (size_t)n * 128 + k;        break;
            case 1:  src = Wu + (size_t)n * 384 + k;        break;
            case 2:  src = We + (size_t)n * 256 + k;        break;
            case 3:  src = We + (size_t)n * 256 + 128 + k;  break;
            case 4:  src = Wu + (size_t)n * 384 + 128 + k;  break;
            default: src = Wu + (size_t)n * 384 + 256 + k;  break;
        }
        unsigned short o[8];
#pragma unroll
        for (int j = 0; j < 8; ++j) o[j] = f2bf(src[j]);
        *(bf16x8*)(wfrag + (size_t)tid * 8) = *(bf16x8*)o;
    } else if (b < 48 + 391) {
        int i = (b - 48) * 256 + t;
        if (i < NNODES) cnt[i] = 0;
    } else {
        int i = (b - 439) * 256 + t;
        if (i < NNODES * DD / 8) {
            float4 v0 = *(const float4*)(x + (size_t)i * 8);
            float4 v1 = *(const float4*)(x + (size_t)i * 8 + 4);
            unsigned short o[8] = { f2bf(v0.x), f2bf(v0.y), f2bf(v0.z), f2bf(v0.w),
                                    f2bf(v1.x), f2bf(v1.y), f2bf(v1.z), f2bf(v1.w) };
            *(bf16x8*)(xb + (size_t)i * 8) = *(bf16x8*)o;
        }
    }
}

// ---------------- CSR build ----------------
__global__ __launch_bounds__(256) void hist_k(const int* __restrict__ ei, int* __restrict__ cnt) {
    int e = blockIdx.x * 256 + threadIdx.x;
    if (e < NEDGES) atomicAdd(&cnt[ei[e]], 1);
}

__global__ __launch_bounds__(SCAN_B) void scan_local(const int* __restrict__ cnt,
                                                     int* __restrict__ off,
                                                     int* __restrict__ bsum) {
    __shared__ int sh[SCAN_B];
    int i = blockIdx.x * SCAN_B + threadIdx.x;
    int v = (i < NNODES) ? cnt[i] : 0;
    sh[threadIdx.x] = v;
    __syncthreads();
    for (int d = 1; d < SCAN_B; d <<= 1) {
        int t = (threadIdx.x >= d) ? sh[threadIdx.x - d] : 0;
        __syncthreads();
        sh[threadIdx.x] += t;
        __syncthreads();
    }
    if (i < NNODES) off[i] = sh[threadIdx.x] - v;
    if (threadIdx.x == SCAN_B - 1) bsum[blockIdx.x] = sh[threadIdx.x];
}

__global__ __launch_bounds__(256) void scan_add2(int* __restrict__ off,
                                                 const int* __restrict__ bsum,
                                                 const int* __restrict__ cnt,
                                                 float* __restrict__ degf) {
    __shared__ int sp;
    int K = blockIdx.x >> 1;
    int t = threadIdx.x;
    if (t < 64) {
        int s = 0;
        for (int j = t; j < K; j += 64) s += bsum[j];
#pragma unroll
        for (int d = 32; d; d >>= 1) s += __shfl_down(s, d, 64);
        if (t == 0) sp = s;
    }
    __syncthreads();
    int i = blockIdx.x * 256 + t;
    if (i < NNODES) {
        off[i] += sp;
        degf[i] = (float)cnt[i];
    }
}

__global__ __launch_bounds__(256) void fill_k(const int* __restrict__ ei,
                                              int* __restrict__ off,
                                              int* __restrict__ edst) {
    int e = blockIdx.x * 256 + threadIdx.x;
    if (e >= NEDGES) return;
    int s = ei[e], d = ei[NEDGES + e];
    int pos = atomicAdd(&off[s], 1);
    edst[pos] = d;
}

// ---------------- aggregate S[v] = sum x[dst] ----------------
// 1 node/wave; 4 edge slots x 16 col-lanes; 2x unrolled (8 gathers in flight).
template <bool IN_BF, bool OUT_BF>
__global__ __launch_bounds__(256) void agg2_k(const int* __restrict__ off,
                                              const int* __restrict__ edst,
                                              const float* __restrict__ xf,
                                              const unsigned short* __restrict__ xb,
                                              float* Sf, unsigned short* Sb) {
    int node = (blockIdx.x * 256 + threadIdx.x) >> 6;
    if (node >= NNODES) return;
    int l = threadIdx.x & 63;
    int es = l >> 4;
    int cg = l & 15;
    int end = off[node];
    int beg = node ? off[node - 1] : 0;
    float acc[8] = {0.f, 0.f, 0.f, 0.f, 0.f, 0.f, 0.f, 0.f};
    float acc2[8] = {0.f, 0.f, 0.f, 0.f, 0.f, 0.f, 0.f, 0.f};
    int e = beg + es;
    for (; e + 4 < end; e += 8) {
        int d0 = edst[e];
        int d1 = edst[e + 4];
        if constexpr (IN_BF) {
            bf16x8 v0 = *(const bf16x8*)(xb + (size_t)d0 * DD + cg * 8);
            bf16x8 v1 = *(const bf16x8*)(xb + (size_t)d1 * DD + cg * 8);
#pragma unroll
            for (int j = 0; j < 8; ++j) {
                acc[j]  += bf2f((unsigned short)v0[j]);
                acc2[j] += bf2f((unsigned short)v1[j]);
            }
        } else {
            const float* p0 = xf + (size_t)d0 * DD + cg * 8;
            const float* p1 = xf + (size_t)d1 * DD + cg * 8;
            float4 a0 = *(const float4*)(p0), a1 = *(const float4*)(p0 + 4);
            float4 b0 = *(const float4*)(p1), b1 = *(const float4*)(p1 + 4);
            acc[0] += a0.x; acc[1] += a0.y; acc[2] += a0.z; acc[3] += a0.w;
            acc[4] += a1.x; acc[5] += a1.y; acc[6] += a1.z; acc[7] += a1.w;
            acc2[0] += b0.x; acc2[1] += b0.y; acc2[2] += b0.z; acc2[3] += b0.w;
            acc2[4] += b1.x; acc2[5] += b1.y; acc2[6] += b1.z; acc2[7] += b1.w;
        }
    }
    if (e < end) {
        int d0 = edst[e];
        if constexpr (IN_BF) {
            bf16x8 v0 = *(const bf16x8*)(xb + (size_t)d0 * DD + cg * 8);
#pragma unroll
            for (int j = 0; j < 8; ++j) acc[j] += bf2f((unsigned short)v0[j]);
        } else {
            const float* p0 = xf + (size_t)d0 * DD + cg * 8;
            float4 a0 = *(const float4*)(p0), a1 = *(const float4*)(p0 + 4);
            acc[0] += a0.x; acc[1] += a0.y; acc[2] += a0.z; acc[3] += a0.w;
            acc[4] += a1.x; acc[5] += a1.y; acc[6] += a1.z; acc[7] += a1.w;
        }
    }
#pragma unroll
    for (int j = 0; j < 8; ++j) {
        acc[j] += acc2[j];
        acc[j] += __shfl_xor(acc[j], 16, 64);
        acc[j] += __shfl_xor(acc[j], 32, 64);
    }
    if (es == 0) {
        if constexpr (OUT_BF) {
            unsigned short o[8];
#pragma unroll
            for (int j = 0; j < 8; ++j) o[j] = f2bf(acc[j]);
            *(bf16x8*)(Sb + (size_t)node * DD + cg * 8) = *(bf16x8*)o;
        } else {
            float4 r0 = { acc[0], acc[1], acc[2], acc[3] };
            float4 r1 = { acc[4], acc[5], acc[6], acc[7] };
            *(float4*)(Sf + (size_t)node * DD + cg * 8) = r0;
            *(float4*)(Sf + (size_t)node * DD + cg * 8 + 4) = r1;
        }
    }
}

// ============ fusedT: transposed GEMM, weights register-resident ============
// preT = W @ [x|S]^T per 16-node frag; lane l16 = node; regs = pre/out cols.
// out[v] = gelu(x@Wn.T+bn)@Wu0.T + gelu(S@Wn.T+deg*bn)@Wu1.T
//        + gelu(deg*(x@We1.T+be)+S@We2.T)@Wu2.T + bu
// NOTE: __launch_bounds__(512, 2) — do NOT raise the min-waves hint: at (512,4)
// the allocator drops to 64 VGPR and spills the 96-VGPR persistent weight set
// to scratch (R9: FETCH 26->402 MB, 2.1x slowdown). Keep VGPR <= 128 so
// 2 blocks/CU (16 waves, 4/SIMD) fit the 512-slot/SIMD VGPR pool.
//
// ONE barrier per iteration (R13): gemm1(i) writes Gs[i&1]; gemm2(i-1) reads
// Gs[(i-1)&1] — disjoint, same interval OK. issueB(i+2) writes XS[(i+2)%3],
// whose previous reader gemm1(i-1) is fenced by this iter's barrier. vmcnt(2):
// 2 issueB in flight x 2 loads, oldest (B(i)) must complete. lgkmcnt(0) makes
// iter i-1's Gs ds_writes visible.
__global__ __launch_bounds__(512, 2) void fusedT_k(const unsigned short* __restrict__ xb,
                                                   const unsigned short* __restrict__ Sb,
                                                   const float* __restrict__ degf,
                                                   const unsigned short* __restrict__ wfrag,
                                                   const float* __restrict__ bn,
                                                   const float* __restrict__ be,
                                                   const float* __restrict__ bu,
                                                   float* __restrict__ out) {
    // XS buf: 8KB x|S rows (XOR-swizzled content) + 256B deg = 8448B, x3 bufs
    __shared__ __align__(16) unsigned short XS[3][4224];
    __shared__ __align__(16) unsigned short Gs[2][6144];   // 16 rows x 768B, swizzled

    const int t = threadIdx.x;
    const int w = t >> 6;
    const int l = t & 63;
    const int l16 = l & 15;
    const int lg = l >> 4;
    const int sw = (l16 & 7) << 4;    // row-XOR swizzle

    // ---- persistent weights: 24 frags = 96 VGPR ----
    bf16x8 wn[4], we1[4], we2[4], wu[12];
#pragma unroll
    for (int kt = 0; kt < 4; ++kt) {
        wn[kt]  = *(const bf16x8*)(wfrag + (size_t)((w * 4 + kt) << 9) + l * 8);
        we1[kt] = *(const bf16x8*)(wfrag + (size_t)((32 + w * 4 + kt) << 9) + l * 8);
        we2[kt] = *(const bf16x8*)(wfrag + (size_t)((64 + w * 4 + kt) << 9) + l * 8);
    }
#pragma unroll
    for (int j = 0; j < 12; ++j)
        wu[j] = *(const bf16x8*)(wfrag + (size_t)((96 + w * 12 + j) << 9) + l * 8);
    f32x4 bnr = *(const f32x4*)(bn + w * 16 + lg * 4);
    f32x4 ber = *(const f32x4*)(be + w * 16 + lg * 4);
    f32x4 bur = *(const f32x4*)(bu + w * 16 + lg * 4);

    const int f0 = blockIdx.x;
    const int nIters = (NFRAGS - f0 + TGRID - 1) / TGRID;   // 12 or 13

    // stage frag f's 16 x-rows + 16 S-rows (8KB) + deg (256B) into XS[buf].
    // content pre-permuted so reads use byte ^ ((row&7)<<4).
    auto issueB = [&](int f, int buf) {
        int fc = (f < NFRAGS) ? f : (NFRAGS - 1);
        int p  = (w << 10) + (l << 4);          // linear byte pos in 8KB
        int po = p & 4095;
        int q  = po ^ (((po >> 8) & 7) << 4);   // pre-permuted source offset
        const unsigned short* base = (w < 4) ? xb : Sb;
        const unsigned short* src = base + (size_t)fc * 2048 + (q >> 1);
        unsigned short* dst = &XS[buf][(size_t)w << 9];    // wave-uniform base
        gload_lds16(src, dst, l);
        gload_lds4(degf + fc * 16 + l16, &XS[buf][4096], l);
    };

    auto gemm1_epi = [&](const unsigned short* xs, unsigned short* gsw) {
        const char* xsb = (const char*)xs;
        bf16x8 bx[4], bs[4];
#pragma unroll
        for (int kt = 0; kt < 4; ++kt) {
            int po = (l16 << 8) + (kt << 6) + (lg << 4);
            bx[kt] = *(const bf16x8*)(xsb + (po ^ sw));
            bs[kt] = *(const bf16x8*)(xsb + 4096 + (po ^ sw));
        }
        float dg = *(const float*)(xsb + 8192 + l16 * 4);
        f32x4 a0 = {0.f,0.f,0.f,0.f}, a1 = a0, a2 = a0, a3 = a0;
        __builtin_amdgcn_s_setprio(1);
#pragma unroll
        for (int kt = 0; kt < 4; ++kt) {
            a0 = MFMA(wn[kt],  bx[kt], a0);
            a1 = MFMA(wn[kt],  bs[kt], a1);
            a2 = MFMA(we1[kt], bx[kt], a2);
            a3 = MFMA(we2[kt], bs[kt], a3);
        }
        __builtin_amdgcn_s_setprio(0);
        u16x4 g0, g1, g2;
#pragma unroll
        for (int r = 0; r < 4; ++r) {
            g0[r] = f2bf(gelu_fast(a0[r] + bnr[r]));
            g1[r] = f2bf(gelu_fast(a1[r] + dg * bnr[r]));
            g2[r] = f2bf(gelu_fast(dg * (a2[r] + ber[r]) + a3[r]));
        }
        char* gb = (char*)gsw;
        int cb = w * 32 + lg * 8;                 // col byte of this lane's 4 cols
        *(u16x4*)(gb + ((l16 * 768 + cb)       ^ sw)) = g0;
        *(u16x4*)(gb + ((l16 * 768 + 256 + cb) ^ sw)) = g1;
        *(u16x4*)(gb + ((l16 * 768 + 512 + cb) ^ sw)) = g2;
    };

    // 3 independent 4-deep MFMA chains.
    auto gemm2_store = [&](int f, const unsigned short* gsr) {
        const char* gb = (const char*)gsr;
        f32x4 o0 = {0.f, 0.f, 0.f, 0.f}, o1 = o0, o2 = o0;
        __builtin_amdgcn_s_setprio(1);
#pragma unroll
        for (int j = 0; j < 4; ++j) {
            bf16x8 ga = *(const bf16x8*)(gb + ((l16 * 768 + (3*j+0) * 64 + lg * 16) ^ sw));
            bf16x8 gc = *(const bf16x8*)(gb + ((l16 * 768 + (3*j+1) * 64 + lg * 16) ^ sw));
            bf16x8 ge = *(const bf16x8*)(gb + ((l16 * 768 + (3*j+2) * 64 + lg * 16) ^ sw));
            o0 = MFMA(wu[3*j+0], ga, o0);
            o1 = MFMA(wu[3*j+1], gc, o1);
            o2 = MFMA(wu[3*j+2], ge, o2);
        }
        __builtin_amdgcn_s_setprio(0);
        f32x4 o = (o0 + o1) + o2;
        int v = f * 16 + l16;
        float4 st = { o[0] + bur[0], o[1] + bur[1], o[2] + bur[2], o[3] + bur[3] };
        *(float4*)(out + (size_t)v * DD + w * 16 + lg * 4) = st;
    };

    // ---- pipeline: ONE barrier per iteration ----
    issueB(f0, 0);                // B(0): 2 vm ops
    issueB(f0 + TGRID, 1);        // B(1): 2 vm ops

    // i = 0 (no gemm2 yet). Outstanding 4 ops; vmcnt(2) -> B(0) complete.
    asm volatile("s_waitcnt vmcnt(2)" ::: "memory");
    __builtin_amdgcn_s_barrier();
    gemm1_epi(&XS[0][0], &Gs[0][0]);
    issueB(f0 + 2 * TGRID, 2);

    for (int i = 1; i < nIters; ++i) {
        // Outstanding: B(i), B(i+1) = 4 ops; vmcnt(2) -> B(i) complete.
        // lgkmcnt(0): this wave's Gs writes from iter i-1 done before barrier.
        asm volatile("s_waitcnt vmcnt(2) lgkmcnt(0)" ::: "memory");
        __builtin_amdgcn_s_barrier();
        gemm1_epi(&XS[i % 3][0], &Gs[i & 1][0]);
        gemm2_store(f0 + (i - 1) * TGRID, &Gs[(i - 1) & 1][0]);
        issueB(f0 + (i + 2) * TGRID, (i + 2) % 3);
    }
    // tail: make gemm1(nIters-1)'s Gs writes visible, then final gemm2.
    asm volatile("s_waitcnt lgkmcnt(0)" ::: "memory");
    __builtin_amdgcn_s_barrier();
    gemm2_store(f0 + (nIters - 1) * TGRID, &Gs[(nIters - 1) & 1][0]);
}

// =============== fallback fused4_k (modes 0/1, unchanged) ===============
#define PREQ(q) do { \
    if ((q) <= 20)      asm volatile("s_waitcnt vmcnt(3)" ::: "memory"); \
    else if ((q) == 21) asm volatile("s_waitcnt vmcnt(2)" ::: "memory"); \
    else if ((q) == 22) asm volatile("s_waitcnt vmcnt(1)" ::: "memory"); \
    else                asm volatile("s_waitcnt vmcnt(0)" ::: "memory"); \
    asm volatile("s_waitcnt lgkmcnt(0)" ::: "memory"); \
    __builtin_amdgcn_s_barrier(); \
    if ((q) + 4 < 24) issue_q((q) + 4); } while (0)

template <int MODE>
__global__ __launch_bounds__(512) void fused4_k(const float* __restrict__ xf,
                                                const unsigned short* __restrict__ xb,
                                                const float* Sf,
                                                const float* __restrict__ degf,
                                                const unsigned short* __restrict__ wfrag,
                                                const float* __restrict__ bn,
                                                const float* __restrict__ be,
                                                const float* __restrict__ bu,
                                                float* out) {
    extern __shared__ char smem[];
    unsigned short* Q  = (unsigned short*)smem;
    unsigned short* Gs = Q + 5 * 4096;
    float* degs = (float*)(Gs + 128 * 136);

    const int t = threadIdx.x;
    const int w = t >> 6;
    const int l = t & 63;
    const int wc = w & 1;
    const int rb = (w >> 1) * 32;
    const int l16 = l & 15;
    const int lg = l >> 4;
    const int node0 = blockIdx.x * 128;

    int r0 = node0 + rb + l16;      if (r0 > NNODES - 1) r0 = NNODES - 1;
    int r1 = node0 + rb + 16 + l16; if (r1 > NNODES - 1) r1 = NNODES - 1;

    auto loadA_bf = [&](const unsigned short* rowp, bf16x8 (&A)[4][2], int f) {
#pragma unroll
        for (int kt = 0; kt < 4; ++kt)
            A[kt][f] = *(const bf16x8*)(rowp + kt * 32 + lg * 8);
    };
    auto loadA_f32 = [&](const float* rowp, bf16x8 (&A)[4][2], int f) {
#pragma unroll
        for (int kt = 0; kt < 4; ++kt) {
            const float* p = rowp + kt * 32 + lg * 8;
            float4 v0 = *(const float4*)(p);
            float4 v1 = *(const float4*)(p + 4);
            bf16x8 a;
            a[0] = (short)f2bf(v0.x); a[1] = (short)f2bf(v0.y);
            a[2] = (short)f2bf(v0.z); a[3] = (short)f2bf(v0.w);
            a[4] = (short)f2bf(v1.x); a[5] = (short)f2bf(v1.y);
            a[6] = (short)f2bf(v1.z); a[7] = (short)f2bf(v1.w);
            A[kt][f] = a;
        }
    };

    bf16x8 aX[4][2], aS[4][2];
    if constexpr (MODE >= 1) {
        loadA_bf(xb + (size_t)r0 * DD, aX, 0);
        loadA_bf(xb + (size_t)r1 * DD, aX, 1);
    } else {
        loadA_f32(xf + (size_t)r0 * DD, aX, 0);
        loadA_f32(xf + (size_t)r1 * DD, aX, 1);
    }
    loadA_f32(Sf + (size_t)r0 * DD, aS, 0);
    loadA_f32(Sf + (size_t)r1 * DD, aS, 1);
    float bnc[4], bec[4], buc[4];
#pragma unroll
    for (int c = 0; c < 4; ++c) {
        int col = (wc * 4 + c) * 16 + l16;
        bnc[c] = bn[col]; bec[c] = be[col]; buc[c] = bu[col];
    }
    if (t < 128) {
        int gr = node0 + t;
        degs[t] = (gr < NNODES) ? degf[gr] : 0.f;
    }

    auto issue_q = [&](int q) {
        const unsigned short* src = wfrag + (size_t)q * 4096 + w * 512 + l * 8;
        unsigned short* dst = Q + (q % 5) * 4096 + w * 512;
        gload_lds16(src, dst, l);
    };
    issue_q(0); issue_q(1); issue_q(2); issue_q(3);

    f32x4 zz = { 0.f, 0.f, 0.f, 0.f };
    f32x4 acc1[2][4], acc2[2][4], acc3[2][4], accO[2][4];
#pragma unroll
    for (int f = 0; f < 2; ++f)
#pragma unroll
        for (int c = 0; c < 4; ++c) {
            acc1[f][c] = zz; acc2[f][c] = zz; acc3[f][c] = zz; accO[f][c] = zz;
        }

    auto bload = [&](int q5, int c) -> bf16x8 {
        return *(const bf16x8*)(Q + q5 * 4096 + (wc * 4 + c) * 512 + l * 8);
    };
    auto body_wn = [&](int kt, int q5) {
        __builtin_amdgcn_s_setprio(1);
#pragma unroll
        for (int c = 0; c < 4; ++c) {
            bf16x8 b = bload(q5, c);
            acc1[0][c] = MFMA(aX[kt][0], b, acc1[0][c]);
            acc1[1][c] = MFMA(aX[kt][1], b, acc1[1][c]);
            acc2[0][c] = MFMA(aS[kt][0], b, acc2[0][c]);
            acc2[1][c] = MFMA(aS[kt][1], b, acc2[1][c]);
        }
        __builtin_amdgcn_s_setprio(0);
    };
    auto body_A = [&](int kt, int q5, bf16x8 (&A)[4][2], f32x4 (&acc)[2][4]) {
        __builtin_amdgcn_s_setprio(1);
#pragma unroll
        for (int c = 0; c < 4; ++c) {
            bf16x8 b = bload(q5, c);
            acc[0][c] = MFMA(A[kt][0], b, acc[0][c]);
            acc[1][c] = MFMA(A[kt][1], b, acc[1][c]);
        }
        __builtin_amdgcn_s_setprio(0);
    };
    auto body_wu = [&](int kt, int q5) {
        bf16x8 g0 = *(const bf16x8*)(Gs + (rb + l16) * 136 + kt * 32 + lg * 8);
        bf16x8 g1 = *(const bf16x8*)(Gs + (rb + 16 + l16) * 136 + kt * 32 + lg * 8);
        __builtin_amdgcn_s_setprio(1);
#pragma unroll
        for (int c = 0; c < 4; ++c) {
            bf16x8 b = bload(q5, c);
            accO[0][c] = MFMA(g0, b, accO[0][c]);
            accO[1][c] = MFMA(g1, b, accO[1][c]);
        }
        __builtin_amdgcn_s_setprio(0);
    };

    float dg[2][4];
    auto epi = [&](f32x4 (&acc)[2][4], const float* bias, int degMode) {
#pragma unroll
        for (int f = 0; f < 2; ++f)
#pragma unroll
            for (int c = 0; c < 4; ++c) {
                int col = (wc * 4 + c) * 16 + l16;
#pragma unroll
                for (int r = 0; r < 4; ++r) {
                    int row = rb + f * 16 + lg * 4 + r;
                    float v = acc[f][c][r];
                    if (degMode == 0) v += bias[c];
                    if (degMode == 1) v += dg[f][r] * bias[c];
                    Gs[row * 136 + col] = f2bf(gelu_fast(v));
                }
            }
    };
    auto fold3 = [&] {
#pragma unroll
        for (int f = 0; f < 2; ++f)
#pragma unroll
            for (int c = 0; c < 4; ++c)
#pragma unroll
                for (int r = 0; r < 4; ++r)
                    acc3[f][c][r] = dg[f][r] * (acc3[f][c][r] + bec[c]);
    };

    PREQ(0);
#pragma unroll
    for (int f = 0; f < 2; ++f)
#pragma unroll
        for (int r = 0; r < 4; ++r)
            dg[f][r] = degs[rb + f * 16 + lg * 4 + r];
    body_wn(0, 0);
    PREQ(1);  body_wn(1, 1);
    PREQ(2);  body_wn(2, 2);
    PREQ(3);  body_wn(3, 3);
    PREQ(4);  epi(acc1, bnc, 0); BARX(); body_wu(0, 4);
    PREQ(5);  body_wu(1, 0);
    PREQ(6);  body_wu(2, 1);
    PREQ(7);  body_wu(3, 2);
    PREQ(8);  body_A(0, 3, aX, acc3);
    PREQ(9);  body_A(1, 4, aX, acc3);
    PREQ(10); body_A(2, 0, aX, acc3);
    PREQ(11); body_A(3, 1, aX, acc3);
    fold3();
    PREQ(12); body_A(0, 2, aS, acc3);
    PREQ(13); body_A(1, 3, aS, acc3);
    PREQ(14); body_A(2, 4, aS, acc3);
    PREQ(15); body_A(3, 0, aS, acc3);
    PREQ(16); epi(acc2, bnc, 1); BARX(); body_wu(0, 1);
    PREQ(17); body_wu(1, 2);
    PREQ(18); body_wu(2, 3);
    PREQ(19); body_wu(3, 4);
    PREQ(20); epi(acc3, nullptr, 2); BARX(); body_wu(0, 0);
    PREQ(21); body_wu(1, 1);
    PREQ(22); body_wu(2, 2);
    PREQ(23); body_wu(3, 3);

#pragma unroll
    for (int f = 0; f < 2; ++f)
#pragma unroll
        for (int c = 0; c < 4; ++c) {
            int col = (wc * 4 + c) * 16 + l16;
#pragma unroll
            for (int r = 0; r < 4; ++r) {
                int grow = node0 + rb + f * 16 + lg * 4 + r;
                if (grow < NNODES)
                    out[(size_t)grow * DD + col] = accO[f][c][r] + buc[c];
            }
        }
}

extern "C" void kernel_launch(void* const* d_in, const int* in_sizes, int n_in,
                              void* d_out, int out_size, void* d_ws, size_t ws_size,
                              hipStream_t stream) {
    const float* x  = (const float*)d_in[0];
    const int*   ei = (const int*)d_in[1];
    const float* Wn = (const float*)d_in[2];
    const float* bn = (const float*)d_in[3];
    const float* We = (const float*)d_in[4];
    const float* be = (const float*)d_in[5];
    const float* Wu = (const float*)d_in[6];
    const float* bu = (const float*)d_in[7];

    float* out = (float*)d_out;

    // ws layout: wfrag(196608) | degf | cnt | off | bsum | edst | xbf | Sbf
    unsigned short* wfrag = (unsigned short*)d_ws;
    float* degf = (float*)((char*)d_ws + 196608);
    int* cnt  = (int*)((char*)d_ws + 596608);
    int* off  = (int*)((char*)d_ws + 996608);
    int* bsum = (int*)((char*)d_ws + 1396608);
    int* edst = (int*)((char*)d_ws + 1398656);
    unsigned short* xbf = (unsigned short*)((char*)d_ws + 3798656);
    unsigned short* Sbf = (unsigned short*)((char*)d_ws + 29398656);

    int mode = 0;
    if (ws_size >= 29398656ULL + 25600000ULL) mode = 2;
    else if (ws_size >= 3798656ULL + 25600000ULL) mode = 1;

    int nb = (NNODES + SCAN_B - 1) / SCAN_B;     // 196

    if (mode == 2) {
        hipMemsetAsync(cnt, 0, (size_t)NNODES * sizeof(int), stream);
        prep1_k<<<P1_H, 256, 0, stream>>>(x, Wn, We, Wu, ei, wfrag, cnt, xbf);
        scan_local<<<nb, SCAN_B, 0, stream>>>(cnt, off, bsum);
        scan_add2<<<(NNODES + 255) / 256, 256, 0, stream>>>(off, bsum, cnt, degf);
        fill_k<<<(NEDGES + 255) / 256, 256, 0, stream>>>(ei, off, edst);
        agg2_k<true, true><<<NNODES / 4, 256, 0, stream>>>(off, edst, x, xbf, nullptr, Sbf);
        fusedT_k<<<TGRID, 512, 0, stream>>>(xbf, Sbf, degf, wfrag, bn, be, bu, out);
    } else {
        int pblocks = (mode >= 1) ? (439 + NNODES * DD / 8 / 256 + 1) : 439;
        prep0_k<<<pblocks, 256, 0, stream>>>(x, Wn, We, Wu, wfrag, cnt, xbf);
        hist_k<<<(NEDGES + 255) / 256, 256, 0, stream>>>(ei, cnt);
        scan_local<<<nb, SCAN_B, 0, stream>>>(cnt, off, bsum);
        scan_add2<<<(NNODES + 255) / 256, 256, 0, stream>>>(off, bsum, cnt, degf);
        fill_k<<<(NEDGES + 255) / 256, 256, 0, stream>>>(ei, off, edst);
        int fblocks = (NNODES + 127) / 128;
        size_t lds_bytes = 5 * 4096 * 2 + 128 * 136 * 2 + 128 * 4;
        if (mode == 1) {
            agg2_k<true, false><<<NNODES / 4, 256, 0, stream>>>(off, edst, x, xbf, out, nullptr);
            fused4_k<1><<<fblocks, 512, lds_bytes, stream>>>(x, xbf, out, degf, wfrag,
                                                             bn, be, bu, out);
        } else {
            agg2_k<false, false><<<NNODES / 4, 256, 0, stream>>>(off, edst, x, nullptr, out, nullptr);
            fused4_k<0><<<fblocks, 512, lds_bytes, stream>>>(x, nullptr, out, degf, wfrag,
                                                             bn, be, bu, out);
        }
    }
}

// Round 14
// 135.337 us; speedup vs baseline: 1.2338x; 1.2338x over previous
//
#include <hip/hip_runtime.h>
#include <hip/hip_bf16.h>
#include <math.h>

#define NNODES 100000
#define NEDGES 600000
#define DD 128
#define SCAN_B 512
#define NFRAGS 6250          // NNODES / 16
#define TGRID 512            // fusedT grid: 2 blocks/CU
#define CAP 64               // bucket capacity (mean deg 6; P(deg>=64) ~ 1e-47)

// prep1 block ranges. x-convert needs NNODES*DD/8/256 = 6250 blocks.
#define P1_W 48
#define P1_X (P1_W + 6250)                   // 6298
#define P1_H (P1_X + (NEDGES + 255) / 256)   // 8642

typedef __attribute__((ext_vector_type(8))) short bf16x8;
typedef __attribute__((ext_vector_type(4))) float f32x4;
typedef __attribute__((ext_vector_type(4))) unsigned short u16x4;

static __device__ __forceinline__ unsigned short f2bf(float f) {
    __hip_bfloat16 h = __float2bfloat16(f);   // HW RNE cvt
    return __builtin_bit_cast(unsigned short, h);
}
static __device__ __forceinline__ float bf2f(unsigned short h) {
    unsigned u = ((unsigned)h) << 16;
    return __builtin_bit_cast(float, u);
}
// tanh-approx GELU via sigmoid, exp2-folded; fast rcp instead of IEEE divide.
// |err| <= ~3e-3 absolute vs exact-erf (threshold 1.07).
static __device__ __forceinline__ float gelu_fast(float v) {
    float w = v * (-2.302203846f - 0.102943150f * v * v);
#if __has_builtin(__builtin_amdgcn_exp2f)
    float e = __builtin_amdgcn_exp2f(w);
#else
    float e = exp2f(w);
#endif
#if __has_builtin(__builtin_amdgcn_rcpf)
    return v * __builtin_amdgcn_rcpf(1.0f + e);
#else
    return v / (1.0f + e);
#endif
}

#if __has_builtin(__builtin_amdgcn_global_load_lds)
#define HAVE_GLDS 1
#else
#define HAVE_GLDS 0
#endif

static __device__ __forceinline__ void gload_lds16(const unsigned short* g, unsigned short* s, int lane) {
#if HAVE_GLDS
    (void)lane;
    __builtin_amdgcn_global_load_lds((const __attribute__((address_space(1))) void*)g,
                                     (__attribute__((address_space(3))) void*)s, 16, 0, 0);
#else
    *(bf16x8*)(s + lane * 8) = *(const bf16x8*)g;
#endif
}
static __device__ __forceinline__ void gload_lds4(const float* g, unsigned short* s, int lane) {
#if HAVE_GLDS
    (void)lane;
    __builtin_amdgcn_global_load_lds((const __attribute__((address_space(1))) void*)g,
                                     (__attribute__((address_space(3))) void*)s, 4, 0, 0);
#else
    *(float*)((char*)s + lane * 4) = *g;
#endif
}

#define MFMA(a, b, c) __builtin_amdgcn_mfma_f32_16x16x32_bf16(a, b, c, 0, 0, 0)
#define BARX() do { asm volatile("s_waitcnt lgkmcnt(0)" ::: "memory"); \
                    __builtin_amdgcn_s_barrier(); } while (0)

// ---------- prep1: weights->fusedT frags | x->bf16 | edge pass ----------
// REQUIRES cnt zeroed beforehand (hipMemsetAsync on the stream).
// BUCKET=false: edge pass = histogram into cnt (mode 2 CSR path).
// BUCKET=true:  edge pass = direct bucket fill bkt[s*CAP+pos] (mode 3).
template <bool BUCKET>
__global__ __launch_bounds__(256) void prep1_k(const float* __restrict__ x,
                                               const float* __restrict__ Wn,
                                               const float* __restrict__ We,
                                               const float* __restrict__ Wu,
                                               const int* __restrict__ ei,
                                               unsigned short* __restrict__ wfrag,
                                               int* __restrict__ cnt,
                                               unsigned short* __restrict__ xb,
                                               int* __restrict__ bkt) {
    int b = blockIdx.x;
    int t = threadIdx.x;
    if (b < P1_W) {
        // frag g: Wn g<32 (nf=g>>2,kt=g&3) | We1 32..63 | We2 64..95 |
        //         Wu 96..191 (nf=gg/12, kt=gg%12)
        int tid = b * 256 + t;
        int l = tid & 63;
        int g = tid >> 6;
        int l16 = l & 15, lg8 = (l >> 4) * 8;
        const float* src;
        if (g < 32)       { int nf = g >> 2,        kt = g & 3;
                            src = Wn + (size_t)(nf * 16 + l16) * 128 + kt * 32 + lg8; }
        else if (g < 64)  { int gg = g - 32; int nf = gg >> 2, kt = gg & 3;
                            src = We + (size_t)(nf * 16 + l16) * 256 + kt * 32 + lg8; }
        else if (g < 96)  { int gg = g - 64; int nf = gg >> 2, kt = gg & 3;
                            src = We + (size_t)(nf * 16 + l16) * 256 + 128 + kt * 32 + lg8; }
        else              { int gg = g - 96; int nf = gg / 12, kt = gg % 12;
                            src = Wu + (size_t)(nf * 16 + l16) * 384 + kt * 32 + lg8; }
        unsigned short o[8];
#pragma unroll
        for (int j = 0; j < 8; ++j) o[j] = f2bf(src[j]);
        *(bf16x8*)(wfrag + (size_t)tid * 8) = *(bf16x8*)o;
    } else if (b < P1_X) {
        int i = (b - P1_W) * 256 + t;          // group of 8 floats
        if (i < NNODES * DD / 8) {
            float4 v0 = *(const float4*)(x + (size_t)i * 8);
            float4 v1 = *(const float4*)(x + (size_t)i * 8 + 4);
            unsigned short o[8] = { f2bf(v0.x), f2bf(v0.y), f2bf(v0.z), f2bf(v0.w),
                                    f2bf(v1.x), f2bf(v1.y), f2bf(v1.z), f2bf(v1.w) };
            *(bf16x8*)(xb + (size_t)i * 8) = *(bf16x8*)o;
        }
    } else {
        int e = (b - P1_X) * 256 + t;
        if (e < NEDGES) {
            if constexpr (BUCKET) {
                int s = ei[e], d = ei[NEDGES + e];
                int pos = atomicAdd(&cnt[s], 1);
                if (pos < CAP) bkt[(size_t)s * CAP + pos] = d;
            } else {
                atomicAdd(&cnt[ei[e]], 1);
            }
        }
    }
}

// ---------- prep0 (fallback modes 0/1): fused4 frag layout | cnt zero | x->bf16 ----------
__global__ __launch_bounds__(256) void prep0_k(const float* __restrict__ x,
                                               const float* __restrict__ Wn,
                                               const float* __restrict__ We,
                                               const float* __restrict__ Wu,
                                               unsigned short* __restrict__ wfrag,
                                               int* __restrict__ cnt,
                                               unsigned short* __restrict__ xb) {
    int b = blockIdx.x;
    int t = threadIdx.x;
    if (b < 48) {
        int tid = b * 256 + t;
        int l = tid & 63;
        int ct = (tid >> 6) & 7;
        int kt = (tid >> 9) & 3;
        int tile = tid >> 11;
        int n = ct * 16 + (l & 15);
        int k = kt * 32 + (l >> 4) * 8;
        const float* src;
        switch (tile) {
            case 0:  src = Wn + (size_t)n * 128 + k;        break;
            case 1:  src = Wu + (size_t)n * 384 + k;        break;
            case 2:  src = We + (size_t)n * 256 + k;        break;
            case 3:  src = We + (size_t)n * 256 + 128 + k;  break;
            case 4:  src = Wu + (size_t)n * 384 + 128 + k;  break;
            default: src = Wu + (size_t)n * 384 + 256 + k;  break;
        }
        unsigned short o[8];
#pragma unroll
        for (int j = 0; j < 8; ++j) o[j] = f2bf(src[j]);
        *(bf16x8*)(wfrag + (size_t)tid * 8) = *(bf16x8*)o;
    } else if (b < 48 + 391) {
        int i = (b - 48) * 256 + t;
        if (i < NNODES) cnt[i] = 0;
    } else {
        int i = (b - 439) * 256 + t;
        if (i < NNODES * DD / 8) {
            float4 v0 = *(const float4*)(x + (size_t)i * 8);
            float4 v1 = *(const float4*)(x + (size_t)i * 8 + 4);
            unsigned short o[8] = { f2bf(v0.x), f2bf(v0.y), f2bf(v0.z), f2bf(v0.w),
                                    f2bf(v1.x), f2bf(v1.y), f2bf(v1.z), f2bf(v1.w) };
            *(bf16x8*)(xb + (size_t)i * 8) = *(bf16x8*)o;
        }
    }
}

// ---------------- CSR build (mode <= 2) ----------------
__global__ __launch_bounds__(256) void hist_k(const int* __restrict__ ei, int* __restrict__ cnt) {
    int e = blockIdx.x * 256 + threadIdx.x;
    if (e < NEDGES) atomicAdd(&cnt[ei[e]], 1);
}

__global__ __launch_bounds__(SCAN_B) void scan_local(const int* __restrict__ cnt,
                                                     int* __restrict__ off,
                                                     int* __restrict__ bsum) {
    __shared__ int sh[SCAN_B];
    int i = blockIdx.x * SCAN_B + threadIdx.x;
    int v = (i < NNODES) ? cnt[i] : 0;
    sh[threadIdx.x] = v;
    __syncthreads();
    for (int d = 1; d < SCAN_B; d <<= 1) {
        int t = (threadIdx.x >= d) ? sh[threadIdx.x - d] : 0;
        __syncthreads();
        sh[threadIdx.x] += t;
        __syncthreads();
    }
    if (i < NNODES) off[i] = sh[threadIdx.x] - v;
    if (threadIdx.x == SCAN_B - 1) bsum[blockIdx.x] = sh[threadIdx.x];
}

__global__ __launch_bounds__(256) void scan_add2(int* __restrict__ off,
                                                 const int* __restrict__ bsum,
                                                 const int* __restrict__ cnt,
                                                 float* __restrict__ degf) {
    __shared__ int sp;
    int K = blockIdx.x >> 1;
    int t = threadIdx.x;
    if (t < 64) {
        int s = 0;
        for (int j = t; j < K; j += 64) s += bsum[j];
#pragma unroll
        for (int d = 32; d; d >>= 1) s += __shfl_down(s, d, 64);
        if (t == 0) sp = s;
    }
    __syncthreads();
    int i = blockIdx.x * 256 + t;
    if (i < NNODES) {
        off[i] += sp;
        degf[i] = (float)cnt[i];
    }
}

__global__ __launch_bounds__(256) void fill_k(const int* __restrict__ ei,
                                              int* __restrict__ off,
                                              int* __restrict__ edst) {
    int e = blockIdx.x * 256 + threadIdx.x;
    if (e >= NEDGES) return;
    int s = ei[e], d = ei[NEDGES + e];
    int pos = atomicAdd(&off[s], 1);
    edst[pos] = d;
}

// ---------------- aggregate S[v] = sum x[dst] (CSR, modes 0-2) ----------------
template <bool IN_BF, bool OUT_BF>
__global__ __launch_bounds__(256) void agg2_k(const int* __restrict__ off,
                                              const int* __restrict__ edst,
                                              const float* __restrict__ xf,
                                              const unsigned short* __restrict__ xb,
                                              float* Sf, unsigned short* Sb) {
    int node = (blockIdx.x * 256 + threadIdx.x) >> 6;
    if (node >= NNODES) return;
    int l = threadIdx.x & 63;
    int es = l >> 4;
    int cg = l & 15;
    int end = off[node];
    int beg = node ? off[node - 1] : 0;
    float acc[8] = {0.f, 0.f, 0.f, 0.f, 0.f, 0.f, 0.f, 0.f};
    float acc2[8] = {0.f, 0.f, 0.f, 0.f, 0.f, 0.f, 0.f, 0.f};
    int e = beg + es;
    for (; e + 4 < end; e += 8) {
        int d0 = edst[e];
        int d1 = edst[e + 4];
        if constexpr (IN_BF) {
            bf16x8 v0 = *(const bf16x8*)(xb + (size_t)d0 * DD + cg * 8);
            bf16x8 v1 = *(const bf16x8*)(xb + (size_t)d1 * DD + cg * 8);
#pragma unroll
            for (int j = 0; j < 8; ++j) {
                acc[j]  += bf2f((unsigned short)v0[j]);
                acc2[j] += bf2f((unsigned short)v1[j]);
            }
        } else {
            const float* p0 = xf + (size_t)d0 * DD + cg * 8;
            const float* p1 = xf + (size_t)d1 * DD + cg * 8;
            float4 a0 = *(const float4*)(p0), a1 = *(const float4*)(p0 + 4);
            float4 b0 = *(const float4*)(p1), b1 = *(const float4*)(p1 + 4);
            acc[0] += a0.x; acc[1] += a0.y; acc[2] += a0.z; acc[3] += a0.w;
            acc[4] += a1.x; acc[5] += a1.y; acc[6] += a1.z; acc[7] += a1.w;
            acc2[0] += b0.x; acc2[1] += b0.y; acc2[2] += b0.z; acc2[3] += b0.w;
            acc2[4] += b1.x; acc2[5] += b1.y; acc2[6] += b1.z; acc2[7] += b1.w;
        }
    }
    if (e < end) {
        int d0 = edst[e];
        if constexpr (IN_BF) {
            bf16x8 v0 = *(const bf16x8*)(xb + (size_t)d0 * DD + cg * 8);
#pragma unroll
            for (int j = 0; j < 8; ++j) acc[j] += bf2f((unsigned short)v0[j]);
        } else {
            const float* p0 = xf + (size_t)d0 * DD + cg * 8;
            float4 a0 = *(const float4*)(p0), a1 = *(const float4*)(p0 + 4);
            acc[0] += a0.x; acc[1] += a0.y; acc[2] += a0.z; acc[3] += a0.w;
            acc[4] += a1.x; acc[5] += a1.y; acc[6] += a1.z; acc[7] += a1.w;
        }
    }
#pragma unroll
    for (int j = 0; j < 8; ++j) {
        acc[j] += acc2[j];
        acc[j] += __shfl_xor(acc[j], 16, 64);
        acc[j] += __shfl_xor(acc[j], 32, 64);
    }
    if (es == 0) {
        if constexpr (OUT_BF) {
            unsigned short o[8];
#pragma unroll
            for (int j = 0; j < 8; ++j) o[j] = f2bf(acc[j]);
            *(bf16x8*)(Sb + (size_t)node * DD + cg * 8) = *(bf16x8*)o;
        } else {
            float4 r0 = { acc[0], acc[1], acc[2], acc[3] };
            float4 r1 = { acc[4], acc[5], acc[6], acc[7] };
            *(float4*)(Sf + (size_t)node * DD + cg * 8) = r0;
            *(float4*)(Sf + (size_t)node * DD + cg * 8 + 4) = r1;
        }
    }
}

// ---------------- aggregate from buckets (mode 3), also emits degf ----------------
__global__ __launch_bounds__(256) void agg3_k(const int* __restrict__ cnt,
                                              const int* __restrict__ bkt,
                                              const unsigned short* __restrict__ xb,
                                              unsigned short* __restrict__ Sb,
                                              float* __restrict__ degf) {
    int node = (blockIdx.x * 256 + threadIdx.x) >> 6;
    if (node >= NNODES) return;
    int l = threadIdx.x & 63;
    int es = l >> 4;
    int cg = l & 15;
    int deg = cnt[node];
    if (l == 0) degf[node] = (float)deg;
    if (deg > CAP) deg = CAP;   // never in practice; memory safety
    const int* bp = bkt + (size_t)node * CAP;
    float acc[8] = {0.f, 0.f, 0.f, 0.f, 0.f, 0.f, 0.f, 0.f};
    float acc2[8] = {0.f, 0.f, 0.f, 0.f, 0.f, 0.f, 0.f, 0.f};
    int e = es;
    for (; e + 4 < deg; e += 8) {
        int d0 = bp[e];
        int d1 = bp[e + 4];
        bf16x8 v0 = *(const bf16x8*)(xb + (size_t)d0 * DD + cg * 8);
        bf16x8 v1 = *(const bf16x8*)(xb + (size_t)d1 * DD + cg * 8);
#pragma unroll
        for (int j = 0; j < 8; ++j) {
            acc[j]  += bf2f((unsigned short)v0[j]);
            acc2[j] += bf2f((unsigned short)v1[j]);
        }
    }
    if (e < deg) {
        int d0 = bp[e];
        bf16x8 v0 = *(const bf16x8*)(xb + (size_t)d0 * DD + cg * 8);
#pragma unroll
        for (int j = 0; j < 8; ++j) acc[j] += bf2f((unsigned short)v0[j]);
    }
#pragma unroll
    for (int j = 0; j < 8; ++j) {
        acc[j] += acc2[j];
        acc[j] += __shfl_xor(acc[j], 16, 64);
        acc[j] += __shfl_xor(acc[j], 32, 64);
    }
    if (es == 0) {
        unsigned short o[8];
#pragma unroll
        for (int j = 0; j < 8; ++j) o[j] = f2bf(acc[j]);
        *(bf16x8*)(Sb + (size_t)node * DD + cg * 8) = *(bf16x8*)o;
    }
}

// ============ fusedT: transposed GEMM, weights register-resident ============
// preT = W @ [x|S]^T per 16-node frag; lane l16 = node; regs = pre/out cols.
// out[v] = gelu(x@Wn.T+bn)@Wu0.T + gelu(S@Wn.T+deg*bn)@Wu1.T
//        + gelu(deg*(x@We1.T+be)+S@We2.T)@Wu2.T + bu
// NOTE: __launch_bounds__(512, 2) — do NOT raise the min-waves hint: at (512,4)
// the allocator drops to 64 VGPR and spills the 96-VGPR persistent weight set
// to scratch (R9: FETCH 26->402 MB, 2.1x slowdown). Keep VGPR <= 128.
//
// Swizzle (R14): FULL 4-bit row XOR (sw = l16<<4). The old 3-bit XOR left each
// half-wave on only 16 of 32 banks (8 dwords/bank vs the 4-dword minimum) ->
// 4.6M SQ_LDS_BANK_CONFLICT. 4-bit spreads each half-wave's b128 reads across
// all 32 banks evenly; Gs 8B-stores stay exactly 2/bank (free).
//
// ONE barrier per iteration (R13): gemm1(i) writes Gs[i&1]; gemm2(i-1) reads
// Gs[(i-1)&1] — disjoint. vmcnt(2): 2 issueB in flight x 2 loads, oldest
// complete. lgkmcnt(0) before barrier makes prior-iter Gs writes visible.
__global__ __launch_bounds__(512, 2) void fusedT_k(const unsigned short* __restrict__ xb,
                                                   const unsigned short* __restrict__ Sb,
                                                   const float* __restrict__ degf,
                                                   const unsigned short* __restrict__ wfrag,
                                                   const float* __restrict__ bn,
                                                   const float* __restrict__ be,
                                                   const float* __restrict__ bu,
                                                   float* __restrict__ out) {
    // XS buf: 8KB x|S rows (XOR-swizzled content) + 256B deg = 8448B, x3 bufs
    __shared__ __align__(16) unsigned short XS[3][4224];
    __shared__ __align__(16) unsigned short Gs[2][6144];   // 16 rows x 768B, swizzled

    const int t = threadIdx.x;
    const int w = t >> 6;
    const int l = t & 63;
    const int l16 = l & 15;
    const int lg = l >> 4;
    const int sw = l16 << 4;          // FULL 4-bit row-XOR swizzle (R14)

    // ---- persistent weights: 24 frags = 96 VGPR ----
    bf16x8 wn[4], we1[4], we2[4], wu[12];
#pragma unroll
    for (int kt = 0; kt < 4; ++kt) {
        wn[kt]  = *(const bf16x8*)(wfrag + (size_t)((w * 4 + kt) << 9) + l * 8);
        we1[kt] = *(const bf16x8*)(wfrag + (size_t)((32 + w * 4 + kt) << 9) + l * 8);
        we2[kt] = *(const bf16x8*)(wfrag + (size_t)((64 + w * 4 + kt) << 9) + l * 8);
    }
#pragma unroll
    for (int j = 0; j < 12; ++j)
        wu[j] = *(const bf16x8*)(wfrag + (size_t)((96 + w * 12 + j) << 9) + l * 8);
    f32x4 bnr = *(const f32x4*)(bn + w * 16 + lg * 4);
    f32x4 ber = *(const f32x4*)(be + w * 16 + lg * 4);
    f32x4 bur = *(const f32x4*)(bu + w * 16 + lg * 4);

    const int f0 = blockIdx.x;
    const int nIters = (NFRAGS - f0 + TGRID - 1) / TGRID;   // 12 or 13

    // stage frag f's 16 x-rows + 16 S-rows (8KB) + deg (256B) into XS[buf].
    // content pre-permuted so reads use byte ^ (row<<4).
    auto issueB = [&](int f, int buf) {
        int fc = (f < NFRAGS) ? f : (NFRAGS - 1);
        int p  = (w << 10) + (l << 4);          // linear byte pos in 8KB
        int po = p & 4095;
        int q  = po ^ (((po >> 8) & 15) << 4);  // pre-permuted source offset (4-bit)
        const unsigned short* base = (w < 4) ? xb : Sb;
        const unsigned short* src = base + (size_t)fc * 2048 + (q >> 1);
        unsigned short* dst = &XS[buf][(size_t)w << 9];    // wave-uniform base
        gload_lds16(src, dst, l);
        gload_lds4(degf + fc * 16 + l16, &XS[buf][4096], l);
    };

    auto gemm1_epi = [&](const unsigned short* xs, unsigned short* gsw) {
        const char* xsb = (const char*)xs;
        bf16x8 bx[4], bs[4];
#pragma unroll
        for (int kt = 0; kt < 4; ++kt) {
            int po = (l16 << 8) + (kt << 6) + (lg << 4);
            bx[kt] = *(const bf16x8*)(xsb + (po ^ sw));
            bs[kt] = *(const bf16x8*)(xsb + 4096 + (po ^ sw));
        }
        float dg = *(const float*)(xsb + 8192 + l16 * 4);
        f32x4 a0 = {0.f,0.f,0.f,0.f}, a1 = a0, a2 = a0, a3 = a0;
        __builtin_amdgcn_s_setprio(1);
#pragma unroll
        for (int kt = 0; kt < 4; ++kt) {
            a0 = MFMA(wn[kt],  bx[kt], a0);
            a1 = MFMA(wn[kt],  bs[kt], a1);
            a2 = MFMA(we1[kt], bx[kt], a2);
            a3 = MFMA(we2[kt], bs[kt], a3);
        }
        __builtin_amdgcn_s_setprio(0);
        u16x4 g0, g1, g2;
#pragma unroll
        for (int r = 0; r < 4; ++r) {
            g0[r] = f2bf(gelu_fast(a0[r] + bnr[r]));
            g1[r] = f2bf(gelu_fast(a1[r] + dg * bnr[r]));
            g2[r] = f2bf(gelu_fast(dg * (a2[r] + ber[r]) + a3[r]));
        }
        char* gb = (char*)gsw;
        int cb = w * 32 + lg * 8;                 // col byte of this lane's 4 cols
        *(u16x4*)(gb + ((l16 * 768 + cb)       ^ sw)) = g0;
        *(u16x4*)(gb + ((l16 * 768 + 256 + cb) ^ sw)) = g1;
        *(u16x4*)(gb + ((l16 * 768 + 512 + cb) ^ sw)) = g2;
    };

    // 3 independent 4-deep MFMA chains.
    auto gemm2_store = [&](int f, const unsigned short* gsr) {
        const char* gb = (const char*)gsr;
        f32x4 o0 = {0.f, 0.f, 0.f, 0.f}, o1 = o0, o2 = o0;
        __builtin_amdgcn_s_setprio(1);
#pragma unroll
        for (int j = 0; j < 4; ++j) {
            bf16x8 ga = *(const bf16x8*)(gb + ((l16 * 768 + (3*j+0) * 64 + lg * 16) ^ sw));
            bf16x8 gc = *(const bf16x8*)(gb + ((l16 * 768 + (3*j+1) * 64 + lg * 16) ^ sw));
            bf16x8 ge = *(const bf16x8*)(gb + ((l16 * 768 + (3*j+2) * 64 + lg * 16) ^ sw));
            o0 = MFMA(wu[3*j+0], ga, o0);
            o1 = MFMA(wu[3*j+1], gc, o1);
            o2 = MFMA(wu[3*j+2], ge, o2);
        }
        __builtin_amdgcn_s_setprio(0);
        f32x4 o = (o0 + o1) + o2;
        int v = f * 16 + l16;
        float4 st = { o[0] + bur[0], o[1] + bur[1], o[2] + bur[2], o[3] + bur[3] };
        *(float4*)(out + (size_t)v * DD + w * 16 + lg * 4) = st;
    };

    // ---- pipeline: ONE barrier per iteration ----
    issueB(f0, 0);                // B(0): 2 vm ops
    issueB(f0 + TGRID, 1);        // B(1): 2 vm ops

    // i = 0 (no gemm2 yet). Outstanding 4 ops; vmcnt(2) -> B(0) complete.
    asm volatile("s_waitcnt vmcnt(2)" ::: "memory");
    __builtin_amdgcn_s_barrier();
    gemm1_epi(&XS[0][0], &Gs[0][0]);
    issueB(f0 + 2 * TGRID, 2);

    for (int i = 1; i < nIters; ++i) {
        asm volatile("s_waitcnt vmcnt(2) lgkmcnt(0)" ::: "memory");
        __builtin_amdgcn_s_barrier();
        gemm1_epi(&XS[i % 3][0], &Gs[i & 1][0]);
        gemm2_store(f0 + (i - 1) * TGRID, &Gs[(i - 1) & 1][0]);
        issueB(f0 + (i + 2) * TGRID, (i + 2) % 3);
    }
    // tail: make gemm1(nIters-1)'s Gs writes visible, then final gemm2.
    asm volatile("s_waitcnt lgkmcnt(0)" ::: "memory");
    __builtin_amdgcn_s_barrier();
    gemm2_store(f0 + (nIters - 1) * TGRID, &Gs[(nIters - 1) & 1][0]);
}

// =============== fallback fused4_k (modes 0/1, unchanged) ===============
#define PREQ(q) do { \
    if ((q) <= 20)      asm volatile("s_waitcnt vmcnt(3)" ::: "memory"); \
    else if ((q) == 21) asm volatile("s_waitcnt vmcnt(2)" ::: "memory"); \
    else if ((q) == 22) asm volatile("s_waitcnt vmcnt(1)" ::: "memory"); \
    else                asm volatile("s_waitcnt vmcnt(0)" ::: "memory"); \
    asm volatile("s_waitcnt lgkmcnt(0)" ::: "memory"); \
    __builtin_amdgcn_s_barrier(); \
    if ((q) + 4 < 24) issue_q((q) + 4); } while (0)

template <int MODE>
__global__ __launch_bounds__(512) void fused4_k(const float* __restrict__ xf,
                                                const unsigned short* __restrict__ xb,
                                                const float* Sf,
                                                const float* __restrict__ degf,
                                                const unsigned short* __restrict__ wfrag,
                                                const float* __restrict__ bn,
                                                const float* __restrict__ be,
                                                const float* __restrict__ bu,
                                                float* out) {
    extern __shared__ char smem[];
    unsigned short* Q  = (unsigned short*)smem;
    unsigned short* Gs = Q + 5 * 4096;
    float* degs = (float*)(Gs + 128 * 136);

    const int t = threadIdx.x;
    const int w = t >> 6;
    const int l = t & 63;
    const int wc = w & 1;
    const int rb = (w >> 1) * 32;
    const int l16 = l & 15;
    const int lg = l >> 4;
    const int node0 = blockIdx.x * 128;

    int r0 = node0 + rb + l16;      if (r0 > NNODES - 1) r0 = NNODES - 1;
    int r1 = node0 + rb + 16 + l16; if (r1 > NNODES - 1) r1 = NNODES - 1;

    auto loadA_bf = [&](const unsigned short* rowp, bf16x8 (&A)[4][2], int f) {
#pragma unroll
        for (int kt = 0; kt < 4; ++kt)
            A[kt][f] = *(const bf16x8*)(rowp + kt * 32 + lg * 8);
    };
    auto loadA_f32 = [&](const float* rowp, bf16x8 (&A)[4][2], int f) {
#pragma unroll
        for (int kt = 0; kt < 4; ++kt) {
            const float* p = rowp + kt * 32 + lg * 8;
            float4 v0 = *(const float4*)(p);
            float4 v1 = *(const float4*)(p + 4);
            bf16x8 a;
            a[0] = (short)f2bf(v0.x); a[1] = (short)f2bf(v0.y);
            a[2] = (short)f2bf(v0.z); a[3] = (short)f2bf(v0.w);
            a[4] = (short)f2bf(v1.x); a[5] = (short)f2bf(v1.y);
            a[6] = (short)f2bf(v1.z); a[7] = (short)f2bf(v1.w);
            A[kt][f] = a;
        }
    };

    bf16x8 aX[4][2], aS[4][2];
    if constexpr (MODE >= 1) {
        loadA_bf(xb + (size_t)r0 * DD, aX, 0);
        loadA_bf(xb + (size_t)r1 * DD, aX, 1);
    } else {
        loadA_f32(xf + (size_t)r0 * DD, aX, 0);
        loadA_f32(xf + (size_t)r1 * DD, aX, 1);
    }
    loadA_f32(Sf + (size_t)r0 * DD, aS, 0);
    loadA_f32(Sf + (size_t)r1 * DD, aS, 1);
    float bnc[4], bec[4], buc[4];
#pragma unroll
    for (int c = 0; c < 4; ++c) {
        int col = (wc * 4 + c) * 16 + l16;
        bnc[c] = bn[col]; bec[c] = be[col]; buc[c] = bu[col];
    }
    if (t < 128) {
        int gr = node0 + t;
        degs[t] = (gr < NNODES) ? degf[gr] : 0.f;
    }

    auto issue_q = [&](int q) {
        const unsigned short* src = wfrag + (size_t)q * 4096 + w * 512 + l * 8;
        unsigned short* dst = Q + (q % 5) * 4096 + w * 512;
        gload_lds16(src, dst, l);
    };
    issue_q(0); issue_q(1); issue_q(2); issue_q(3);

    f32x4 zz = { 0.f, 0.f, 0.f, 0.f };
    f32x4 acc1[2][4], acc2[2][4], acc3[2][4], accO[2][4];
#pragma unroll
    for (int f = 0; f < 2; ++f)
#pragma unroll
        for (int c = 0; c < 4; ++c) {
            acc1[f][c] = zz; acc2[f][c] = zz; acc3[f][c] = zz; accO[f][c] = zz;
        }

    auto bload = [&](int q5, int c) -> bf16x8 {
        return *(const bf16x8*)(Q + q5 * 4096 + (wc * 4 + c) * 512 + l * 8);
    };
    auto body_wn = [&](int kt, int q5) {
        __builtin_amdgcn_s_setprio(1);
#pragma unroll
        for (int c = 0; c < 4; ++c) {
            bf16x8 b = bload(q5, c);
            acc1[0][c] = MFMA(aX[kt][0], b, acc1[0][c]);
            acc1[1][c] = MFMA(aX[kt][1], b, acc1[1][c]);
            acc2[0][c] = MFMA(aS[kt][0], b, acc2[0][c]);
            acc2[1][c] = MFMA(aS[kt][1], b, acc2[1][c]);
        }
        __builtin_amdgcn_s_setprio(0);
    };
    auto body_A = [&](int kt, int q5, bf16x8 (&A)[4][2], f32x4 (&acc)[2][4]) {
        __builtin_amdgcn_s_setprio(1);
#pragma unroll
        for (int c = 0; c < 4; ++c) {
            bf16x8 b = bload(q5, c);
            acc[0][c] = MFMA(A[kt][0], b, acc[0][c]);
            acc[1][c] = MFMA(A[kt][1], b, acc[1][c]);
        }
        __builtin_amdgcn_s_setprio(0);
    };
    auto body_wu = [&](int kt, int q5) {
        bf16x8 g0 = *(const bf16x8*)(Gs + (rb + l16) * 136 + kt * 32 + lg * 8);
        bf16x8 g1 = *(const bf16x8*)(Gs + (rb + 16 + l16) * 136 + kt * 32 + lg * 8);
        __builtin_amdgcn_s_setprio(1);
#pragma unroll
        for (int c = 0; c < 4; ++c) {
            bf16x8 b = bload(q5, c);
            accO[0][c] = MFMA(g0, b, accO[0][c]);
            accO[1][c] = MFMA(g1, b, accO[1][c]);
        }
        __builtin_amdgcn_s_setprio(0);
    };

    float dg[2][4];
    auto epi = [&](f32x4 (&acc)[2][4], const float* bias, int degMode) {
#pragma unroll
        for (int f = 0; f < 2; ++f)
#pragma unroll
            for (int c = 0; c < 4; ++c) {
                int col = (wc * 4 + c) * 16 + l16;
#pragma unroll
                for (int r = 0; r < 4; ++r) {
                    int row = rb + f * 16 + lg * 4 + r;
                    float v = acc[f][c][r];
                    if (degMode == 0) v += bias[c];
                    if (degMode == 1) v += dg[f][r] * bias[c];
                    Gs[row * 136 + col] = f2bf(gelu_fast(v));
                }
            }
    };
    auto fold3 = [&] {
#pragma unroll
        for (int f = 0; f < 2; ++f)
#pragma unroll
            for (int c = 0; c < 4; ++c)
#pragma unroll
                for (int r = 0; r < 4; ++r)
                    acc3[f][c][r] = dg[f][r] * (acc3[f][c][r] + bec[c]);
    };

    PREQ(0);
#pragma unroll
    for (int f = 0; f < 2; ++f)
#pragma unroll
        for (int r = 0; r < 4; ++r)
            dg[f][r] = degs[rb + f * 16 + lg * 4 + r];
    body_wn(0, 0);
    PREQ(1);  body_wn(1, 1);
    PREQ(2);  body_wn(2, 2);
    PREQ(3);  body_wn(3, 3);
    PREQ(4);  epi(acc1, bnc, 0); BARX(); body_wu(0, 4);
    PREQ(5);  body_wu(1, 0);
    PREQ(6);  body_wu(2, 1);
    PREQ(7);  body_wu(3, 2);
    PREQ(8);  body_A(0, 3, aX, acc3);
    PREQ(9);  body_A(1, 4, aX, acc3);
    PREQ(10); body_A(2, 0, aX, acc3);
    PREQ(11); body_A(3, 1, aX, acc3);
    fold3();
    PREQ(12); body_A(0, 2, aS, acc3);
    PREQ(13); body_A(1, 3, aS, acc3);
    PREQ(14); body_A(2, 4, aS, acc3);
    PREQ(15); body_A(3, 0, aS, acc3);
    PREQ(16); epi(acc2, bnc, 1); BARX(); body_wu(0, 1);
    PREQ(17); body_wu(1, 2);
    PREQ(18); body_wu(2, 3);
    PREQ(19); body_wu(3, 4);
    PREQ(20); epi(acc3, nullptr, 2); BARX(); body_wu(0, 0);
    PREQ(21); body_wu(1, 1);
    PREQ(22); body_wu(2, 2);
    PREQ(23); body_wu(3, 3);

#pragma unroll
    for (int f = 0; f < 2; ++f)
#pragma unroll
        for (int c = 0; c < 4; ++c) {
            int col = (wc * 4 + c) * 16 + l16;
#pragma unroll
            for (int r = 0; r < 4; ++r) {
                int grow = node0 + rb + f * 16 + lg * 4 + r;
                if (grow < NNODES)
                    out[(size_t)grow * DD + col] = accO[f][c][r] + buc[c];
            }
        }
}

extern "C" void kernel_launch(void* const* d_in, const int* in_sizes, int n_in,
                              void* d_out, int out_size, void* d_ws, size_t ws_size,
                              hipStream_t stream) {
    const float* x  = (const float*)d_in[0];
    const int*   ei = (const int*)d_in[1];
    const float* Wn = (const float*)d_in[2];
    const float* bn = (const float*)d_in[3];
    const float* We = (const float*)d_in[4];
    const float* be = (const float*)d_in[5];
    const float* Wu = (const float*)d_in[6];
    const float* bu = (const float*)d_in[7];

    float* out = (float*)d_out;

    // ws layout: wfrag(196608) | degf | cnt | off | bsum | edst | xbf | Sbf | bkt
    unsigned short* wfrag = (unsigned short*)d_ws;
    float* degf = (float*)((char*)d_ws + 196608);
    int* cnt  = (int*)((char*)d_ws + 596608);
    int* off  = (int*)((char*)d_ws + 996608);
    int* bsum = (int*)((char*)d_ws + 1396608);
    int* edst = (int*)((char*)d_ws + 1398656);
    unsigned short* xbf = (unsigned short*)((char*)d_ws + 3798656);
    unsigned short* Sbf = (unsigned short*)((char*)d_ws + 29398656);
    int* bkt = (int*)((char*)d_ws + 54998656);   // NNODES*CAP*4 = 25.6 MB

    int mode = 0;
    if (ws_size >= 54998656ULL + (size_t)NNODES * CAP * 4) mode = 3;
    else if (ws_size >= 54998656ULL) mode = 2;
    else if (ws_size >= 29398656ULL) mode = 1;

    int nb = (NNODES + SCAN_B - 1) / SCAN_B;     // 196

    if (mode == 3) {
        // 4-dispatch path: memset | prep(w+x+bucket-fill) | agg(buckets) | fusedT
        hipMemsetAsync(cnt, 0, (size_t)NNODES * sizeof(int), stream);
        prep1_k<true><<<P1_H, 256, 0, stream>>>(x, Wn, We, Wu, ei, wfrag, cnt, xbf, bkt);
        agg3_k<<<NNODES / 4, 256, 0, stream>>>(cnt, bkt, xbf, Sbf, degf);
        fusedT_k<<<TGRID, 512, 0, stream>>>(xbf, Sbf, degf, wfrag, bn, be, bu, out);
    } else if (mode == 2) {
        hipMemsetAsync(cnt, 0, (size_t)NNODES * sizeof(int), stream);
        prep1_k<false><<<P1_H, 256, 0, stream>>>(x, Wn, We, Wu, ei, wfrag, cnt, xbf, nullptr);
        scan_local<<<nb, SCAN_B, 0, stream>>>(cnt, off, bsum);
        scan_add2<<<(NNODES + 255) / 256, 256, 0, stream>>>(off, bsum, cnt, degf);
        fill_k<<<(NEDGES + 255) / 256, 256, 0, stream>>>(ei, off, edst);
        agg2_k<true, true><<<NNODES / 4, 256, 0, stream>>>(off, edst, x, xbf, nullptr, Sbf);
        fusedT_k<<<TGRID, 512, 0, stream>>>(xbf, Sbf, degf, wfrag, bn, be, bu, out);
    } else {
        int pblocks = (mode >= 1) ? (439 + NNODES * DD / 8 / 256 + 1) : 439;
        prep0_k<<<pblocks, 256, 0, stream>>>(x, Wn, We, Wu, wfrag, cnt, xbf);
        hist_k<<<(NEDGES + 255) / 256, 256, 0, stream>>>(ei, cnt);
        scan_local<<<nb, SCAN_B, 0, stream>>>(cnt, off, bsum);
        scan_add2<<<(NNODES + 255) / 256, 256, 0, stream>>>(off, bsum, cnt, degf);
        fill_k<<<(NEDGES + 255) / 256, 256, 0, stream>>>(ei, off, edst);
        int fblocks = (NNODES + 127) / 128;
        size_t lds_bytes = 5 * 4096 * 2 + 128 * 136 * 2 + 128 * 4;
        if (mode == 1) {
            agg2_k<true, false><<<NNODES / 4, 256, 0, stream>>>(off, edst, x, xbf, out, nullptr);
            fused4_k<1><<<fblocks, 512, lds_bytes, stream>>>(x, xbf, out, degf, wfrag,
                                                             bn, be, bu, out);
        } else {
            agg2_k<false, false><<<NNODES / 4, 256, 0, stream>>>(off, edst, x, nullptr, out, nullptr);
            fused4_k<0><<<fblocks, 512, lds_bytes, stream>>>(x, nullptr, out, degf, wfrag,
                                                             bn, be, bu, out);
        }
    }
}